// Round 8
// baseline (450.395 us; speedup 1.0000x reference)
//
#include <hip/hip_runtime.h>

#define T_STEPS 512
#define HID 64

typedef short bf16x8 __attribute__((ext_vector_type(8)));
typedef float f32x4 __attribute__((ext_vector_type(4)));

__device__ __forceinline__ float sigm(float x) {
  return __builtin_amdgcn_rcpf(1.f + __expf(-x));
}
__device__ __forceinline__ float tanh_fast(float x) {
  return 1.f - 2.f * __builtin_amdgcn_rcpf(__expf(2.f * x) + 1.f);
}

// split fp32 -> bf16 hi (chop) + bf16 lo (chop of exact residual)
__device__ __forceinline__ void split1(float v, short* hi, short* lo) {
  unsigned u = __float_as_uint(v);
  float r = v - __uint_as_float(u & 0xffff0000u);   // exact in fp32
  *hi = (short)(u >> 16);
  *lo = (short)(__float_as_uint(r) >> 16);
}

__device__ __forceinline__ void split8(const float* __restrict__ p, bf16x8& hi, bf16x8& lo) {
  float v[8];
  *(float4*)&v[0] = *(const float4*)p;
  *(float4*)&v[4] = *(const float4*)(p + 4);
  #pragma unroll
  for (int i = 0; i < 8; ++i) {
    unsigned u = __float_as_uint(v[i]);
    float r = v[i] - __uint_as_float(u & 0xffff0000u);
    hi[i] = (short)(u >> 16);
    lo[i] = (short)(__float_as_uint(r) >> 16);
  }
}

#define MM(acc, A, B) acc = __builtin_amdgcn_mfma_f32_16x16x32_bf16((A), (B), (acc), 0, 0, 0)

// depth-4 chain vs {Wh0,Wh1,Wl0,Wl1}: per M-row r holding value v_r,
// acc[row] = v_r·(Wh+Wl).  With hi/lo packed in adjacent rows,
// acc[0]+acc[1] (h rows) or acc[2]+acc[3] (v rows) = full product, exact.
#define GP4(acc, V0, V1, NM) do { \
    MM(acc, V0, NM##h0); MM(acc, V1, NM##h1); \
    MM(acc, V0, NM##l0); MM(acc, V1, NM##l1); } while (0)

#define WFRAG(NM, Wp, goff) \
  bf16x8 NM##h0, NM##l0, NM##h1, NM##l1; \
  split8((Wp) + (goff) * (64 * HID) + wrowoff, NM##h0, NM##l0); \
  split8((Wp) + (goff) * (64 * HID) + wrowoff + 32, NM##h1, NM##l1)

// LDS A-matrices: logical [m(16)][k(64)] bf16, XOR-swizzled in 16B units:
// element idx (shorts) = m*64 + (((k>>3) ^ (m&7))<<3) + (k&7). Conflict-free b128.
//
// R11: merged HV operand matrix. Batch b occupies ALL 4 of its M-rows:
//   4b: h_hi, 4b+1: h_lo, 4b+2: v_hi, 4b+3: v_lo.
// The same (HV0,HV1) fragments feed Whh MFMAs (valid acc[0..1], garbage
// acc[2..3] ignored) AND Wih MFMAs (valid acc[2..3]). LDS reads per wave
// halve: 4 -> 2 ds_read_b128. ArrL0 = {hA,x} (L0's operands), ArrL1 =
// {hB,hA} (L1's). L0 writes h into both arrays. Arithmetic bit-identical.
__global__ __launch_bounds__(512, 2) void gru_mfma(
    const float* __restrict__ x,
    const float* __restrict__ Wih0, const float* __restrict__ Whh0,
    const float* __restrict__ bih0, const float* __restrict__ bhh0,
    const float* __restrict__ Wih1, const float* __restrict__ Whh1,
    const float* __restrict__ bih1, const float* __restrict__ bhh1,
    const float* __restrict__ W1, const float* __restrict__ b1,
    const float* __restrict__ W2, const float* __restrict__ b2,
    float* __restrict__ out)
{
  const int tid   = threadIdx.x;
  const int lane  = tid & 63;
  const int wv    = tid >> 6;      // 0..7
  const int wq    = wv & 3;        // j-chunk
  const int layer = wv >> 2;       // 0: GRU layer 0, 1: GRU layer 1
  const int nloc  = lane & 15;
  const int quad  = lane >> 4;
  const int b0    = blockIdx.x << 2;

  __shared__ __align__(16) short aL0[2][1024];   // rows: {hA hi/lo, x hi/lo}
  __shared__ __align__(16) short aL1[2][1024];   // rows: {hB hi/lo, hA hi/lo}
  __shared__ float hfin[256];
  __shared__ float msf[128];

  // ---- per-layer weight/bias selection (wave-uniform) ----
  const float* Wih  = layer ? Wih1 : Wih0;
  const float* Whh  = layer ? Whh1 : Whh0;
  const float* bihp = layer ? bih1 : bih0;
  const float* bhhp = layer ? bhh1 : bhh0;

  const int wrowoff = (16 * wq + nloc) * HID + 8 * quad;
  WFRAG(ir, Wih, 0); WFRAG(iz, Wih, 1); WFRAG(in, Wih, 2);
  WFRAG(hr, Whh, 0); WFRAG(hz, Whh, 1); WFRAG(hn, Whh, 2);

  const int jg = 16 * wq + nloc;
  const float b_r = bihp[jg] + bhhp[jg];
  const float b_z = bihp[jg + 64] + bhhp[jg + 64];
  const float b_i = bihp[jg + 128], b_h = bhhp[jg + 128];

  // loop-invariant LDS indices (shorts)
  const int ra0 = nloc * 64 + (((quad    ) ^ (nloc & 7)) << 3);
  const int ra1 = nloc * 64 + (((quad + 4) ^ (nloc & 7)) << 3);
  // h -> own array rows 4q (hi), 4q+1 (lo)
  const int hwrH  = quad * 256 +       (((jg >> 3) ^ ( (quad & 1) << 2)       ) << 3) + (jg & 7);
  const int hwrL  = quad * 256 +  64 + (((jg >> 3) ^ (((quad & 1) << 2) | 1)) << 3) + (jg & 7);
  // L0's h copy -> aL1 rows 4q+2 (hi), 4q+3 (lo)
  const int hwr2H = quad * 256 + 128 + (((jg >> 3) ^ (((quad & 1) << 2) | 2)) << 3) + (jg & 7);
  const int hwr2L = quad * 256 + 192 + (((jg >> 3) ^ (((quad & 1) << 2) | 3)) << 3) + (jg & 7);
  // x -> aL0 rows 4wq+2 (hi), 4wq+3 (lo)
  const int xwrH  = wq * 256 + 128 + (((lane >> 3) ^ (((wq & 1) << 2) | 2)) << 3) + (lane & 7);
  const int xwrL  = wq * 256 + 192 + (((lane >> 3) ^ (((wq & 1) << 2) | 3)) << 3) + (lane & 7);

  short* Ar      = layer ? &aL1[0][0] : &aL0[0][0];  // wave's own read/write array
  short* aL1flat = &aL1[0][0];
  short* aL0flat = &aL0[0][0];

  const float* xptr = x + ((size_t)(b0 + wq) * HID + lane) * T_STEPS;

  for (int i = tid; i < 2048; i += 512) { aL0flat[i] = 0; aL1flat[i] = 0; }
  __syncthreads();
  // iter 0 reads buf1: L0 seeds x(0) into aL0[1] v-rows (h rows stay 0)
  if (!layer) { short h, l; split1(xptr[0], &h, &l);
                aL0flat[1024 + xwrH] = h; aL0flat[1024 + xwrL] = l; }
  __syncthreads();

  float hp = 0.f;   // L0: hA[quad][jg]; L1: hB[quad][jg], lagging one step

  // One GRU step for this wave's role.  RB/WB = compile-time short offsets.
  // x(TT+1) read wraps at TT=511: lands in a buffer never read again.
  #define STEP_BODY(RB, WB, F0, TT) do { \
    bf16x8 HV0 = *(const bf16x8*)&Ar[(RB) + ra0], HV1 = *(const bf16x8*)&Ar[(RB) + ra1]; \
    float xn = 0.f; \
    if (!layer) xn = xptr[((TT) + 1) & (T_STEPS - 1)]; \
    f32x4 sRh = {b_r, 0.f, 0.f, 0.f}, sRx = {0.f, 0.f, 0.f, 0.f}; \
    f32x4 sZh = {b_z, 0.f, 0.f, 0.f}, sZx = {0.f, 0.f, 0.f, 0.f}; \
    f32x4 sHh = {b_h, 0.f, 0.f, 0.f}, sIx = {0.f, 0.f, b_i, 0.f}; \
    __builtin_amdgcn_s_setprio(1); \
    GP4(sRh, HV0, HV1, hr); GP4(sRx, HV0, HV1, ir); \
    GP4(sZh, HV0, HV1, hz); GP4(sZx, HV0, HV1, iz); \
    float rr = sigm((sRx[2] + sRx[3]) + (sRh[0] + sRh[1])); \
    float zz = sigm((sZx[2] + sZx[3]) + (sZh[0] + sZh[1])); \
    GP4(sHh, HV0, HV1, hn); GP4(sIx, HV0, HV1, in); \
    __builtin_amdgcn_s_setprio(0); \
    float n = tanh_fast((sIx[2] + sIx[3]) + rr * (sHh[0] + sHh[1])); \
    float hnew = n + zz * (hp - n); \
    hp = ((F0) && layer && (TT) == 0) ? 0.f : hnew; \
    { short h, l; split1(hp, &h, &l); \
      Ar[(WB) + hwrH] = h; Ar[(WB) + hwrL] = l; \
      if (!layer) { aL1flat[(WB) + hwr2H] = h; aL1flat[(WB) + hwr2L] = l; } } \
    if (!layer) { short h, l; split1(xn, &h, &l); \
                  aL0flat[(WB) + xwrH] = h; aL0flat[(WB) + xwrL] = l; } \
    __syncthreads(); \
  } while (0)

  #pragma unroll 1
  for (int t = 0; t < T_STEPS; t += 2) {
    STEP_BODY(1024, 0, 1, t);        // even t: read buf1, write buf0
    STEP_BODY(0, 1024, 0, t + 1);    // odd t:  read buf0, write buf1
  }
  #undef STEP_BODY

  // ---- epilogue: L1 waves compute layer1 step T-1 ----
  // after iter T-1 (WB=1024): aL1[1] = {hB(T-2) rows, hA(T-1) rows}
  if (layer) {
    const f32x4 z4 = {0.f, 0.f, 0.f, 0.f};
    bf16x8 HV0 = *(const bf16x8*)&Ar[1024 + ra0], HV1 = *(const bf16x8*)&Ar[1024 + ra1];
    f32x4 sRh = z4, sZh = z4, sHh = z4, sRx = z4, sZx = z4, sIx = z4;
    GP4(sRh, HV0, HV1, hr);
    GP4(sRx, HV0, HV1, ir);
    GP4(sZh, HV0, HV1, hz);
    GP4(sZx, HV0, HV1, iz);
    GP4(sHh, HV0, HV1, hn);
    GP4(sIx, HV0, HV1, in);
    float r  = sigm((sRx[2] + sRx[3]) + (sRh[0] + sRh[1]) + b_r);
    float zz = sigm((sZx[2] + sZx[3]) + (sZh[0] + sZh[1]) + b_z);
    float n  = tanh_fast(((sIx[2] + sIx[3]) + b_i) + r * ((sHh[0] + sHh[1]) + b_h));
    hp = n + zz * (hp - n);
    hfin[quad * 64 + jg] = hp;
  }
  __syncthreads();

  // ---- classifier on hfin = hB(T-1), fp32 ----
  if (tid < 128) {
    const int bb = tid >> 5, u = tid & 31;
    float acc = b1[u];
    const float* w1r = W1 + u * HID;
    #pragma unroll
    for (int k = 0; k < 64; ++k)
      acc = fmaf(w1r[k], hfin[bb * 64 + k], acc);
    msf[(bb << 5) + u] = fmaxf(acc, 0.f);
  }
  __syncthreads();
  if (tid < 16) {
    const int bb = tid >> 2, c = tid & 3;
    float acc = b2[c];
    const float* w2r = W2 + (c << 5);
    #pragma unroll
    for (int u = 0; u < 32; ++u)
      acc = fmaf(w2r[u], msf[(bb << 5) + u], acc);
    out[(size_t)(b0 + bb) * 4 + c] = acc;
  }
}

extern "C" void kernel_launch(void* const* d_in, const int* in_sizes, int n_in,
                              void* d_out, int out_size, void* d_ws, size_t ws_size,
                              hipStream_t stream) {
  const float* x    = (const float*)d_in[0];
  const float* Wih0 = (const float*)d_in[1];
  const float* Whh0 = (const float*)d_in[2];
  const float* bih0 = (const float*)d_in[3];
  const float* bhh0 = (const float*)d_in[4];
  const float* Wih1 = (const float*)d_in[5];
  const float* Whh1 = (const float*)d_in[6];
  const float* bih1 = (const float*)d_in[7];
  const float* bhh1 = (const float*)d_in[8];
  const float* W1   = (const float*)d_in[9];
  const float* b1   = (const float*)d_in[10];
  const float* W2   = (const float*)d_in[11];
  const float* b2   = (const float*)d_in[12];
  float* out = (float*)d_out;

  hipLaunchKernelGGL(gru_mfma, dim3(256), dim3(512), 0, stream,
                     x, Wih0, Whh0, bih0, bhh0, Wih1, Whh1, bih1, bhh1,
                     W1, b1, W2, b2, out);
}

// Round 9
// 368.478 us; speedup vs baseline: 1.2223x; 1.2223x over previous
//
#include <hip/hip_runtime.h>

#define T_STEPS 512
#define HID 64

typedef _Float16 f16x8 __attribute__((ext_vector_type(8)));
typedef float f32x4 __attribute__((ext_vector_type(4)));

__device__ __forceinline__ float sigm(float x) {
  return __builtin_amdgcn_rcpf(1.f + __expf(-x));
}
__device__ __forceinline__ float tanh_fast(float x) {
  return 1.f - 2.f * __builtin_amdgcn_rcpf(__expf(2.f * x) + 1.f);
}

// split fp32 -> fp16 hi (round-nearest) + fp16 lo (residual). hi+lo ~ v to 2^-22.
__device__ __forceinline__ void split1(float v, short* hi, short* lo) {
  _Float16 h = (_Float16)v;
  float r = v - (float)h;            // exact in fp32 (h within half-ulp of v)
  _Float16 l = (_Float16)r;
  union { _Float16 f; short s; } uh, ul;
  uh.f = h; ul.f = l;
  *hi = uh.s; *lo = ul.s;
}

__device__ __forceinline__ void cvt8(const float* __restrict__ p, f16x8& w) {
  float v[8];
  *(float4*)&v[0] = *(const float4*)p;
  *(float4*)&v[4] = *(const float4*)(p + 4);
  #pragma unroll
  for (int i = 0; i < 8; ++i) w[i] = (_Float16)v[i];
}

#define MM(acc, A, B) acc = __builtin_amdgcn_mfma_f32_16x16x32_f16((A), (B), (acc), 0, 0, 0)

// R12 fp16 scheme: weights SINGLE fp16 (2^-11 rel, replaces bf16 hi+lo pair);
// values keep hi/lo M-rows (4b: v_hi, 4b+1: v_lo -> exact to ~2^-22).
// One depth-2 chain per gate-side: acc[0]+acc[1] = (vh+vl)·W16.
// 12 MFMA/wave (was 24) -> SIMD issue floor halves.
#define GP2(acc, V0, V1, NM) do { MM(acc, V0, NM##c0); MM(acc, V1, NM##c1); } while (0)

#define WFRAG(NM, Wp, goff) \
  f16x8 NM##c0, NM##c1; \
  cvt8((Wp) + (goff) * (64 * HID) + wrowoff, NM##c0); \
  cvt8((Wp) + (goff) * (64 * HID) + wrowoff + 32, NM##c1)

// LDS A-matrices: logical [m(16)][k(64)] fp16 (bits in shorts), XOR-swizzled in
// 16B units: element idx = m*64 + (((k>>3) ^ (m&7))<<3) + (k&7). Conflict-free
// b128 reads. Batch b: v_hi at row 4b, v_lo at row 4b+1; rows 4b+2,3 stay zero.
//
// Structure = R10 (verified): wave specialization by layer (waves 0-3 = L0,
// 4-7 = L1; 2 waves/SIMD), single barrier/step, setprio around MFMA cluster,
// biases folded into MFMA C-init, 2x unrolled ping-pong.
__global__ __launch_bounds__(512, 2) void gru_mfma(
    const float* __restrict__ x,
    const float* __restrict__ Wih0, const float* __restrict__ Whh0,
    const float* __restrict__ bih0, const float* __restrict__ bhh0,
    const float* __restrict__ Wih1, const float* __restrict__ Whh1,
    const float* __restrict__ bih1, const float* __restrict__ bhh1,
    const float* __restrict__ W1, const float* __restrict__ b1,
    const float* __restrict__ W2, const float* __restrict__ b2,
    float* __restrict__ out)
{
  const int tid   = threadIdx.x;
  const int lane  = tid & 63;
  const int wv    = tid >> 6;      // 0..7
  const int wq    = wv & 3;        // j-chunk
  const int layer = wv >> 2;       // 0: GRU layer 0, 1: GRU layer 1
  const int nloc  = lane & 15;
  const int quad  = lane >> 4;
  const int b0    = blockIdx.x << 2;

  __shared__ __align__(16) short xs[2][1024];
  __shared__ __align__(16) short hA[2][1024];
  __shared__ __align__(16) short hB[2][1024];
  __shared__ float hfin[256];
  __shared__ float msf[128];

  // ---- per-layer weight/bias selection (wave-uniform) ----
  const float* Wih  = layer ? Wih1 : Wih0;
  const float* Whh  = layer ? Whh1 : Whh0;
  const float* bihp = layer ? bih1 : bih0;
  const float* bhhp = layer ? bhh1 : bhh0;

  const int wrowoff = (16 * wq + nloc) * HID + 8 * quad;
  WFRAG(ir, Wih, 0); WFRAG(iz, Wih, 1); WFRAG(in, Wih, 2);
  WFRAG(hr, Whh, 0); WFRAG(hz, Whh, 1); WFRAG(hn, Whh, 2);

  const int jg = 16 * wq + nloc;
  const float b_r = bihp[jg] + bhhp[jg];
  const float b_z = bihp[jg + 64] + bhhp[jg + 64];
  const float b_i = bihp[jg + 128], b_h = bhhp[jg + 128];

  // loop-invariant LDS indices (shorts)
  const int ra0 = nloc * 64 + (((quad    ) ^ (nloc & 7)) << 3);
  const int ra1 = nloc * 64 + (((quad + 4) ^ (nloc & 7)) << 3);
  const int hwrH = quad * 256 +      (((jg >> 3) ^ ( (quad & 1) << 2)     ) << 3) + (jg & 7);
  const int hwrL = quad * 256 + 64 + (((jg >> 3) ^ (((quad & 1) << 2) | 1)) << 3) + (jg & 7);
  const int xwrH = wq * 256 +      (((lane >> 3) ^ ( (wq & 1) << 2)     ) << 3) + (lane & 7);
  const int xwrL = wq * 256 + 64 + (((lane >> 3) ^ (((wq & 1) << 2) | 1)) << 3) + (lane & 7);

  // own-h array (written by this wave's role) and input array (read-only here):
  // L0: own = hA, in = xs;   L1: own = hB, in = hA.
  short* Hown = layer ? &hB[0][0] : &hA[0][0];
  short* Vin  = layer ? &hA[0][0] : &xs[0][0];

  const float* xptr = x + ((size_t)(b0 + wq) * HID + lane) * T_STEPS;

  for (int i = tid; i < 2048; i += 512) {
    ((short*)xs)[i] = 0; ((short*)hA)[i] = 0; ((short*)hB)[i] = 0;
  }
  __syncthreads();
  // iter 0 reads buffer 1: L0 seeds x(0) there (hA, hB stay zero = h(-1))
  if (!layer) { short h, l; split1(xptr[0], &h, &l); xs[1][xwrH] = h; xs[1][xwrL] = l; }
  __syncthreads();

  float hp = 0.f;   // L0: hA[quad][jg]; L1: hB[quad][jg], lagging one step

  // One GRU step for this wave's role.  RB/WB = compile-time short offsets.
  // x(TT+1) read wraps at TT=511: lands in a buffer never read again.
  #define STEP_BODY(RB, WB, F0, TT) do { \
    f16x8 H0 = *(const f16x8*)&Hown[(RB) + ra0], H1 = *(const f16x8*)&Hown[(RB) + ra1]; \
    f16x8 V0 = *(const f16x8*)&Vin[(RB) + ra0],  V1 = *(const f16x8*)&Vin[(RB) + ra1]; \
    float xn = 0.f; \
    if (!layer) xn = xptr[((TT) + 1) & (T_STEPS - 1)]; \
    f32x4 sRh = {b_r, 0.f, 0.f, 0.f}, sRx = {0.f, 0.f, 0.f, 0.f}; \
    f32x4 sZh = {b_z, 0.f, 0.f, 0.f}, sZx = {0.f, 0.f, 0.f, 0.f}; \
    f32x4 sHh = {b_h, 0.f, 0.f, 0.f}, sIx = {b_i, 0.f, 0.f, 0.f}; \
    __builtin_amdgcn_s_setprio(1); \
    GP2(sRh, H0, H1, hr); GP2(sRx, V0, V1, ir); \
    GP2(sZh, H0, H1, hz); GP2(sZx, V0, V1, iz); \
    float rr = sigm((sRx[0] + sRx[1]) + (sRh[0] + sRh[1])); \
    float zz = sigm((sZx[0] + sZx[1]) + (sZh[0] + sZh[1])); \
    GP2(sHh, H0, H1, hn); GP2(sIx, V0, V1, in); \
    __builtin_amdgcn_s_setprio(0); \
    float n = tanh_fast((sIx[0] + sIx[1]) + rr * (sHh[0] + sHh[1])); \
    float hnew = n + zz * (hp - n); \
    hp = ((F0) && layer && (TT) == 0) ? 0.f : hnew; \
    { short h, l; split1(hp, &h, &l); Hown[(WB) + hwrH] = h; Hown[(WB) + hwrL] = l; } \
    if (!layer) { short h, l; split1(xn, &h, &l); \
                  ((short*)xs)[(WB) + xwrH] = h; ((short*)xs)[(WB) + xwrL] = l; } \
    __syncthreads(); \
  } while (0)

  #pragma unroll 1
  for (int t = 0; t < T_STEPS; t += 2) {
    STEP_BODY(1024, 0, 1, t);        // even t: read buf1, write buf0
    STEP_BODY(0, 1024, 0, t + 1);    // odd t:  read buf0, write buf1
  }
  #undef STEP_BODY

  // ---- epilogue: L1 waves compute layer1 step T-1 ----
  // after iter T-1 (WB=1024): hA[1] = hA(T-1), hB[1] = hB(T-2)
  if (layer) {
    const f32x4 z4 = {0.f, 0.f, 0.f, 0.f};
    const int rb = 1 << 10;
    f16x8 H0 = *(const f16x8*)&Hown[rb + ra0], H1 = *(const f16x8*)&Hown[rb + ra1];
    f16x8 V0 = *(const f16x8*)&Vin[rb + ra0],  V1 = *(const f16x8*)&Vin[rb + ra1];
    f32x4 sRh = z4, sZh = z4, sHh = z4, sRx = z4, sZx = z4, sIx = z4;
    GP2(sRh, H0, H1, hr);
    GP2(sRx, V0, V1, ir);
    GP2(sZh, H0, H1, hz);
    GP2(sZx, V0, V1, iz);
    GP2(sHh, H0, H1, hn);
    GP2(sIx, V0, V1, in);
    float r  = sigm((sRx[0] + sRx[1]) + (sRh[0] + sRh[1]) + b_r);
    float zz = sigm((sZx[0] + sZx[1]) + (sZh[0] + sZh[1]) + b_z);
    float n  = tanh_fast(((sIx[0] + sIx[1]) + b_i) + r * ((sHh[0] + sHh[1]) + b_h));
    hp = n + zz * (hp - n);
    hfin[quad * 64 + jg] = hp;
  }
  __syncthreads();

  // ---- classifier on hfin = hB(T-1), fp32 ----
  if (tid < 128) {
    const int bb = tid >> 5, u = tid & 31;
    float acc = b1[u];
    const float* w1r = W1 + u * HID;
    #pragma unroll
    for (int k = 0; k < 64; ++k)
      acc = fmaf(w1r[k], hfin[bb * 64 + k], acc);
    msf[(bb << 5) + u] = fmaxf(acc, 0.f);
  }
  __syncthreads();
  if (tid < 16) {
    const int bb = tid >> 2, c = tid & 3;
    float acc = b2[c];
    const float* w2r = W2 + (c << 5);
    #pragma unroll
    for (int u = 0; u < 32; ++u)
      acc = fmaf(w2r[u], msf[(bb << 5) + u], acc);
    out[(size_t)(b0 + bb) * 4 + c] = acc;
  }
}

extern "C" void kernel_launch(void* const* d_in, const int* in_sizes, int n_in,
                              void* d_out, int out_size, void* d_ws, size_t ws_size,
                              hipStream_t stream) {
  const float* x    = (const float*)d_in[0];
  const float* Wih0 = (const float*)d_in[1];
  const float* Whh0 = (const float*)d_in[2];
  const float* bih0 = (const float*)d_in[3];
  const float* bhh0 = (const float*)d_in[4];
  const float* Wih1 = (const float*)d_in[5];
  const float* Whh1 = (const float*)d_in[6];
  const float* bih1 = (const float*)d_in[7];
  const float* bhh1 = (const float*)d_in[8];
  const float* W1   = (const float*)d_in[9];
  const float* b1   = (const float*)d_in[10];
  const float* W2   = (const float*)d_in[11];
  const float* b2   = (const float*)d_in[12];
  float* out = (float*)d_out;

  hipLaunchKernelGGL(gru_mfma, dim3(256), dim3(512), 0, stream,
                     x, Wih0, Whh0, bih0, bhh0, Wih1, Whh1, bih1, bhh1,
                     W1, b1, W2, b2, out);
}